// Round 15
// baseline (160.817 us; speedup 1.0000x reference)
//
#include <hip/hip_runtime.h>
#include <math.h>

#define NN 100000
#define NE 1600000
#define DIN 256
#define DHID 128
#define NCLS 64
#define NEG_SLOPE 0.2f

#define NBUCK 196          // ceil(NN / 512), bucket = dst >> 9
#define ECAP 10240         // fixed per-bucket ebuf capacity (mean 8192, +22 sigma)
#define CHUNK 4096
#define NCHB ((NE + CHUNK - 1) / CHUNK)   // 391
#define PREPB 16

#define NGRP 16384         // edge-balanced 16-lane groups for aggregate
#define G1 ((NN + 127) / 128)             // 782 gemm1 blocks

typedef __bf16 bf16_t;
typedef bf16_t bf16x8 __attribute__((ext_vector_type(8)));
typedef float f32x4 __attribute__((ext_vector_type(4)));
typedef ushort ushort8v __attribute__((ext_vector_type(8)));

__device__ __forceinline__ ushort f2bf(float f) {
    union { float f; unsigned u; } c; c.f = f;
    unsigned u = c.u;
    unsigned r = (u + 0x7FFFu + ((u >> 16) & 1u)) >> 16;
    return (ushort)r;
}
__device__ __forceinline__ float bf2f(ushort b) {
    return __uint_as_float(((unsigned)b) << 16);
}

// ================= kA: weight prep + gcur zero =================
__global__ __launch_bounds__(256) void k_prep(const float* __restrict__ W,
                                              const float* __restrict__ fcW,
                                              ushort* __restrict__ Wt,
                                              ushort* __restrict__ fcWt,
                                              int* __restrict__ gcur) {
    int t = blockIdx.x * 256 + threadIdx.x;
    if (blockIdx.x == 0) gcur[threadIdx.x] = 0;
    for (int i = t; i < DHID * DIN; i += PREPB * 256) {   // Wt[n][k]
        int n = i >> 8, k = i & 255;
        Wt[i] = f2bf(W[k * DHID + n]);
    }
    for (int i = t; i < NCLS * DHID; i += PREPB * 256) {  // fcWt[n][k]
        int n = i >> 7, k = i & 127;
        fcWt[i] = f2bf(fcW[k * NCLS + n]);
    }
}

// ================= kB: k_bin ∪ gemm1 (depth-2 prefetch) =================
union SmemB {
    struct {                      // k_bin branch (~30 KB)
        int hist[NBUCK];
        int scn[256];
        int loff[NBUCK];
        int cur[NBUCK];
        int gb[NBUCK];
        unsigned ord[CHUNK];
        ushort obk[CHUNK];
    } b;
    struct {                      // gemm1 branch (~65 KB)
        ushort Xs[2][8192];
        ushort Wl[2][8192];
        float Al[DHID];
        float Ar[DHID];
    } g;
};

#define ISSUE(XA, WA, KC) do { \
    int k0g_ = (KC) * 64; \
    _Pragma("unroll") \
    for (int i_ = 0; i_ < 4; i_++) { \
        int grow_ = row0 + srow[i_]; \
        if (grow_ < NN) { \
            const float4* p_ = (const float4*)(X + (size_t)grow_ * DIN + k0g_ + ske[i_]); \
            XA[i_][0] = p_[0]; XA[i_][1] = p_[1]; \
        } else { \
            XA[i_][0] = make_float4(0.f,0.f,0.f,0.f); \
            XA[i_][1] = make_float4(0.f,0.f,0.f,0.f); \
        } \
        WA[i_] = *(const uint4*)(Wt + (size_t)srow[i_] * DIN + k0g_ + ske[i_]); \
    } \
} while (0)

#define COMMIT(XA, WA, BUF) do { \
    _Pragma("unroll") \
    for (int i_ = 0; i_ < 4; i_++) { \
        int o_ = i_ * 4096 + t * 16; \
        ushort8v bb_; \
        bb_[0] = f2bf(XA[i_][0].x); bb_[1] = f2bf(XA[i_][0].y); \
        bb_[2] = f2bf(XA[i_][0].z); bb_[3] = f2bf(XA[i_][0].w); \
        bb_[4] = f2bf(XA[i_][1].x); bb_[5] = f2bf(XA[i_][1].y); \
        bb_[6] = f2bf(XA[i_][1].z); bb_[7] = f2bf(XA[i_][1].w); \
        *(ushort8v*)((char*)&sm.g.Xs[BUF][0] + o_) = bb_; \
        *(uint4*)((char*)&sm.g.Wl[BUF][0] + o_) = WA[i_]; \
    } \
} while (0)

#define COMPUTE(BUF) do { \
    const char* xb_ = (const char*)&sm.g.Xs[BUF][0]; \
    const char* wb_ = (const char*)&sm.g.Wl[BUF][0]; \
    _Pragma("unroll") \
    for (int k0_ = 0; k0_ < 2; k0_++) { \
        int kb_ = k0_ * 64 + kgrp; \
        bf16x8 a_[2], b_[8]; \
        _Pragma("unroll") \
        for (int r_ = 0; r_ < 2; r_++) { \
            int row_ = rbase + r_ * 16 + lcol; \
            a_[r_] = *(const bf16x8*)(xb_ + row_ * 128 + (kb_ ^ ((row_ & 7) << 4))); \
        } \
        _Pragma("unroll") \
        for (int cc_ = 0; cc_ < 8; cc_++) { \
            int n_ = cc_ * 16 + lcol; \
            b_[cc_] = *(const bf16x8*)(wb_ + n_ * 128 + (kb_ ^ ((n_ & 7) << 4))); \
        } \
        _Pragma("unroll") \
        for (int r_ = 0; r_ < 2; r_++) \
            _Pragma("unroll") \
            for (int cc_ = 0; cc_ < 8; cc_++) \
                acc[r_][cc_] = __builtin_amdgcn_mfma_f32_16x16x32_bf16(a_[r_], b_[cc_], acc[r_][cc_], 0, 0, 0); \
    } \
} while (0)

__global__ __launch_bounds__(256, 2) void fused_bin_gemm1(
        const int* __restrict__ src, const int* __restrict__ dst,
        int* __restrict__ gcur, unsigned* __restrict__ ebuf,
        const float* __restrict__ X, const ushort* __restrict__ Wt,
        const float* __restrict__ attn_l, const float* __restrict__ attn_r,
        ushort* __restrict__ featb, float* __restrict__ el, float* __restrict__ er) {
    __shared__ SmemB sm;
    const int t = threadIdx.x;

    if (blockIdx.x < NCHB) {
        // ---- k_bin branch ----
        const int base = blockIdx.x * CHUNK;
        int cnt = NE - base; if (cnt > CHUNK) cnt = CHUNK;

        for (int i = t; i < NBUCK; i += 256) sm.b.hist[i] = 0;
        __syncthreads();

        unsigned vals[16];
        int bks[16];
#pragma unroll
        for (int i = 0; i < 16; i++) {
            int idx = base + i * 256 + t;
            if (idx < NE) {
                int d = dst[idx], s = src[idx];
                int bb = d >> 9;
                bks[i] = bb;
                vals[i] = ((unsigned)(d & 511) << 17) | (unsigned)s;
                atomicAdd(&sm.b.hist[bb], 1);
            } else bks[i] = -1;
        }
        __syncthreads();

        int hv = (t < NBUCK) ? sm.b.hist[t] : 0;
        sm.b.scn[t] = hv;
        __syncthreads();
        for (int d = 1; d < 256; d <<= 1) {
            int a = (t >= d) ? sm.b.scn[t - d] : 0;
            __syncthreads();
            sm.b.scn[t] += a;
            __syncthreads();
        }
        if (t < NBUCK) { sm.b.loff[t] = sm.b.scn[t] - hv; sm.b.cur[t] = sm.b.scn[t] - hv; }
        __syncthreads();

#pragma unroll
        for (int i = 0; i < 16; i++) {
            if (bks[i] >= 0) {
                int slot = atomicAdd(&sm.b.cur[bks[i]], 1);
                sm.b.ord[slot] = vals[i];
                sm.b.obk[slot] = (ushort)bks[i];
            }
        }
        if (t < NBUCK && hv > 0) sm.b.gb[t] = t * ECAP + atomicAdd(&gcur[t], hv);
        __syncthreads();

        for (int s = t; s < cnt; s += 256) {
            int bb = sm.b.obk[s];
            ebuf[sm.b.gb[bb] + (s - sm.b.loff[bb])] = sm.b.ord[s];
        }
        return;
    }

    // ---- gemm1 branch (depth-2 pipelined) ----
    const int row0 = (blockIdx.x - NCHB) * 128;
    if (t < 128) { sm.g.Al[t] = attn_l[t]; sm.g.Ar[t] = attn_r[t]; }

    int srow[4], ske[4];
#pragma unroll
    for (int i = 0; i < 4; i++) {
        int o = i * 4096 + t * 16;
        int row = o >> 7;
        int bl = (o & 127) ^ ((row & 7) << 4);
        srow[i] = row;
        ske[i] = bl >> 1;
    }

    const int w = t >> 6, lane = t & 63;
    const int rbase = w * 32;
    const int lcol = lane & 15;
    const int kgrp = (lane >> 4) * 16;

    f32x4 acc[2][8];
#pragma unroll
    for (int r = 0; r < 2; r++)
#pragma unroll
        for (int c = 0; c < 8; c++) acc[r][c] = (f32x4){0.f, 0.f, 0.f, 0.f};

    float4 xA[4][2], xB[4][2];
    uint4  wA[4], wB[4];

    ISSUE(xA, wA, 0); COMMIT(xA, wA, 0);
    ISSUE(xB, wB, 1);
    __syncthreads();
    ISSUE(xA, wA, 2); COMPUTE(0); COMMIT(xB, wB, 1); __syncthreads();
    ISSUE(xB, wB, 3); COMPUTE(1); COMMIT(xA, wA, 0); __syncthreads();
    COMPUTE(0); COMMIT(xB, wB, 1); __syncthreads();
    COMPUTE(1);

    // epilogue: stage bf16 tile (reuses Xs+Wl first 32KB region via Xs)
    __syncthreads();
    ushort* Os = (ushort*)sm.g.Xs;
#pragma unroll
    for (int r = 0; r < 2; r++)
#pragma unroll
        for (int cc = 0; cc < 8; cc++)
#pragma unroll
            for (int i = 0; i < 4; i++) {
                int rloc = rbase + r * 16 + (lane >> 4) * 4 + i;
                int col = cc * 16 + lcol;
                Os[rloc * 128 + col] = f2bf(acc[r][cc][i]);
            }
    __syncthreads();

    // fused el/er: 2 threads per row, row-rotated LDS reads
    {
        int row = t >> 1, half = t & 1;
        int grow = row0 + row;
        const ushort* orow = Os + row * 128 + half * 64;
        const float* alp = sm.g.Al + half * 64;
        const float* arp = sm.g.Ar + half * 64;
        float pl = 0.f, pr = 0.f;
        int rot = row & 7;
#pragma unroll
        for (int qq = 0; qq < 8; qq++) {
            int q = (qq + rot) & 7;
            ushort8v f8 = *(const ushort8v*)(orow + q * 8);
#pragma unroll
            for (int e = 0; e < 8; e++) {
                float fe = bf2f(f8[e]);
                pl += fe * alp[q * 8 + e];
                pr += fe * arp[q * 8 + e];
            }
        }
        pl += __shfl_down(pl, 1);
        pr += __shfl_down(pr, 1);
        if (!half && grow < NN) { el[grow] = pl; er[grow] = pr; }
    }

#pragma unroll
    for (int i = 0; i < 8; i++) {
        int u = i * 256 + t;
        int row = u >> 4;
        int grow = row0 + row;
        if (grow < NN)
            *(uint4*)(featb + (size_t)grow * 128 + (u & 15) * 8) =
                *(uint4*)((char*)Os + u * 16);
    }
}

// ================= kC: k_csr + local group-boundary resolution (1024 thr) =================
__global__ __launch_bounds__(1024) void fused_csr(const unsigned* __restrict__ ebuf,
                                                  const int* __restrict__ gcur,
                                                  int* __restrict__ off_g,
                                                  int* __restrict__ deg_g,
                                                  int* __restrict__ ssrc,
                                                  int* __restrict__ nsplit) {
    __shared__ int sdeg[512];
    __shared__ int pr[256];
    __shared__ int lofs[512];
    __shared__ int scnt[512];
    __shared__ int sb[2];   // [0]=bpre_b, [1]=total
    const int b = blockIdx.x, t = threadIdx.x;
    const int node0 = b << 9;
    const int ebase = b * ECAP;
    const int ecnt = gcur[b];

    // bucket prefix (196 entries, t<256 active in scan)
    if (t < 256) pr[t] = (t < NBUCK) ? gcur[t] : 0;
    __syncthreads();
    for (int d = 1; d < 256; d <<= 1) {
        int a = 0;
        if (t < 256 && t >= d) a = pr[t - d];
        __syncthreads();
        if (t < 256) pr[t] += a;
        __syncthreads();
    }
    if (t == 0) { sb[0] = pr[b] - ecnt; sb[1] = pr[NBUCK - 1]; }
    if (t < 512) sdeg[t] = 0;
    __syncthreads();

    for (int s = t; s < ecnt; s += 1024)
        atomicAdd(&sdeg[ebuf[ebase + s] >> 17], 1);
    __syncthreads();

    int d0 = 0, d1 = 0;
    if (t < 256) { d0 = sdeg[2 * t]; d1 = sdeg[2 * t + 1]; pr[t] = d0 + d1; }
    __syncthreads();
    for (int d = 1; d < 256; d <<= 1) {
        int a = 0;
        if (t < 256 && t >= d) a = pr[t - d];
        __syncthreads();
        if (t < 256) pr[t] += a;
        __syncthreads();
    }
    if (t < 256) {
        int ex = pr[t] - d0 - d1;
        lofs[2 * t] = ex;
        lofs[2 * t + 1] = ex + d0;
        scnt[2 * t] = 0; scnt[2 * t + 1] = 0;
        int n0 = node0 + 2 * t, n1 = n0 + 1;
        if (n0 < NN) { off_g[n0] = ebase + ex;      deg_g[n0] = d0; }
        if (n1 < NN) { off_g[n1] = ebase + ex + d0; deg_g[n1] = d1; }
    }
    __syncthreads();

    // scatter
    for (int s = t; s < ecnt; s += 1024) {
        unsigned v = ebuf[ebase + s];
        int dl = v >> 17;
        int c = atomicAdd(&scnt[dl], 1);
        ssrc[ebase + lofs[dl] + c] = (int)(v & 0x1FFFFu);
    }

    // group boundaries whose targets land in this bucket's real-edge range
    {
        long bpre_b = sb[0], total = sb[1];
        if (total > 0 && ecnt > 0) {
            long glo = (bpre_b * NGRP + total - 1) / total;
            long ghi = ((bpre_b + ecnt) * NGRP + total - 1) / total;
            if (ghi > NGRP) ghi = NGRP;
            for (long g = glo + t; g < ghi; g += 1024) {
                long target = g * total / NGRP;
                int lt = (int)(target - bpre_b);
                int lo = 0, hi = 512;
                while (lo < hi) {
                    int m = (lo + hi) >> 1;
                    if (lofs[m] < lt) lo = m + 1; else hi = m;
                }
                int node = node0 + lo;
                if (node > NN) node = NN;
                nsplit[g] = node;
            }
        }
        if (b == 0 && t == 0) nsplit[NGRP] = NN;
    }
}

// ================= kE: aggregate (full-row, 4-deep, nsplit array) =================
__global__ __launch_bounds__(256) void aggregate(const int* __restrict__ off,
                                                 const int* __restrict__ deg,
                                                 const int* __restrict__ ssrc,
                                                 const float* __restrict__ el,
                                                 const float* __restrict__ er,
                                                 const ushort* __restrict__ featb,
                                                 ushort* __restrict__ hb,
                                                 const int* __restrict__ nsplit) {
    const int gid = blockIdx.x * 16 + (threadIdx.x >> 4);
    const int lc = threadIdx.x & 15;
    int n = nsplit[gid];
    const int nend = nsplit[gid + 1];
    const ushort* fb = featb + lc * 8;

    for (; n < nend; ++n) {
        const int e0 = off[n];
        const int dg = deg[n];
        const float erd = er[n];
        float acc[8];
#pragma unroll
        for (int q = 0; q < 8; q++) acc[q] = 0.f;
        float wsum = 0.f;

        int j = 0;
        for (; j + 4 <= dg; j += 4) {
            int s0 = ssrc[e0 + j + 0];
            int s1 = ssrc[e0 + j + 1];
            int s2 = ssrc[e0 + j + 2];
            int s3 = ssrc[e0 + j + 3];
            ushort8v f0 = *(const ushort8v*)(fb + (size_t)s0 * DHID);
            ushort8v f1 = *(const ushort8v*)(fb + (size_t)s1 * DHID);
            ushort8v f2 = *(const ushort8v*)(fb + (size_t)s2 * DHID);
            ushort8v f3 = *(const ushort8v*)(fb + (size_t)s3 * DHID);
            float x0 = el[s0] + erd, x1 = el[s1] + erd;
            float x2 = el[s2] + erd, x3 = el[s3] + erd;
            x0 = x0 > 0.f ? x0 : NEG_SLOPE * x0;
            x1 = x1 > 0.f ? x1 : NEG_SLOPE * x1;
            x2 = x2 > 0.f ? x2 : NEG_SLOPE * x2;
            x3 = x3 > 0.f ? x3 : NEG_SLOPE * x3;
            float w0 = __expf(x0), w1 = __expf(x1);
            float w2 = __expf(x2), w3 = __expf(x3);
            wsum += (w0 + w1) + (w2 + w3);
#pragma unroll
            for (int q = 0; q < 8; q++)
                acc[q] += (w0 * bf2f(f0[q]) + w1 * bf2f(f1[q])) +
                          (w2 * bf2f(f2[q]) + w3 * bf2f(f3[q]));
        }
        for (; j < dg; ++j) {
            int s0 = ssrc[e0 + j];
            ushort8v f0 = *(const ushort8v*)(fb + (size_t)s0 * DHID);
            float x0 = el[s0] + erd;
            x0 = x0 > 0.f ? x0 : NEG_SLOPE * x0;
            float w0 = __expf(x0);
            wsum += w0;
#pragma unroll
            for (int q = 0; q < 8; q++) acc[q] += w0 * bf2f(f0[q]);
        }

        float inv = (dg > 0) ? 1.0f / wsum : 0.f;
        ushort8v o8;
#pragma unroll
        for (int q = 0; q < 8; q++) o8[q] = f2bf(acc[q] * inv);
        *(ushort8v*)(hb + (size_t)n * DHID + lc * 8) = o8;
    }
}

// ================= kF: GEMM2 =================
__global__ __launch_bounds__(256, 3) void gemm2(const ushort* __restrict__ hb,
                                                const ushort* __restrict__ fcWt,
                                                const float* __restrict__ fcb,
                                                float* __restrict__ out) {
    __shared__ ushort Hs[128 * 128];   // 32 KB
    __shared__ ushort Fs[64 * 128];    // 16 KB
    const int t = threadIdx.x;
    const int row0 = blockIdx.x * 128;

    {
#pragma unroll
        for (int i = 0; i < 8; i++) {
            int u = i * 256 + t;
            int row = u >> 4;
            int grow = row0 + row;
            uint4 v = make_uint4(0, 0, 0, 0);
            if (grow < NN) v = *(const uint4*)(hb + (size_t)grow * 128 + (u & 15) * 8);
            int byte_off = row * 256 + (((u & 15) * 16) ^ ((row & 7) << 4));
            *(uint4*)((char*)Hs + byte_off) = v;
        }
#pragma unroll
        for (int i = 0; i < 4; i++) {
            int u = i * 256 + t;
            int n = u >> 4;
            int byte_off = n * 256 + (((u & 15) * 16) ^ ((n & 7) << 4));
            *(uint4*)((char*)Fs + byte_off) = ((const uint4*)fcWt)[u];
        }
    }

    const int w = t >> 6, lane = t & 63;
    const int rbase = w * 32;
    const int lcol = lane & 15;
    const int kgrp = (lane >> 4) * 16;

    f32x4 acc[2][4];
#pragma unroll
    for (int c = 0; c < 4; c++) {
        float bias = fcb[c * 16 + lcol];
#pragma unroll
        for (int r = 0; r < 2; r++)
#pragma unroll
            for (int i = 0; i < 4; i++) acc[r][c][i] = bias;
    }
    __syncthreads();

#pragma unroll
    for (int k0 = 0; k0 < 4; k0++) {
        int kbyte = k0 * 64 + kgrp;
        bf16x8 a[2], b[4];
#pragma unroll
        for (int r = 0; r < 2; r++) {
            int row = rbase + r * 16 + lcol;
            a[r] = *(bf16x8*)((char*)Hs + row * 256 + (kbyte ^ ((row & 7) << 4)));
        }
#pragma unroll
        for (int c = 0; c < 4; c++) {
            int n = c * 16 + lcol;
            b[c] = *(bf16x8*)((char*)Fs + n * 256 + (kbyte ^ ((n & 7) << 4)));
        }
#pragma unroll
        for (int r = 0; r < 2; r++)
#pragma unroll
            for (int c = 0; c < 4; c++)
                acc[r][c] = __builtin_amdgcn_mfma_f32_16x16x32_bf16(a[r], b[c], acc[r][c], 0, 0, 0);
    }

#pragma unroll
    for (int r = 0; r < 2; r++)
#pragma unroll
        for (int i = 0; i < 4; i++) {
            int row = rbase + r * 16 + (lane >> 4) * 4 + i;
            int grow = row0 + row;
            if (grow < NN) {
                float* op = out + (size_t)grow * 64 + lcol;
#pragma unroll
                for (int c = 0; c < 4; c++) op[c * 16] = acc[r][c][i];
            }
        }
}

// ---------------- launch ----------------
extern "C" void kernel_launch(void* const* d_in, const int* in_sizes, int n_in,
                              void* d_out, int out_size, void* d_ws, size_t ws_size,
                              hipStream_t stream) {
    const float* X      = (const float*)d_in[0];
    const float* W      = (const float*)d_in[1];
    const float* attn_l = (const float*)d_in[2];
    const float* attn_r = (const float*)d_in[3];
    const float* fcW    = (const float*)d_in[4];
    const float* fcb    = (const float*)d_in[5];
    const int*   src    = (const int*)d_in[6];
    const int*   dst    = (const int*)d_in[7];
    float* out = (float*)d_out;

    char* ws = (char*)d_ws;
    ushort* featb = (ushort*)ws;            ws += (size_t)NN * DHID * 2;
    ushort* hb    = (ushort*)ws;            ws += (size_t)NN * DHID * 2;
    ushort* Wt    = (ushort*)ws;            ws += (size_t)DHID * DIN * 2;
    ushort* fcWt  = (ushort*)ws;            ws += (size_t)NCLS * DHID * 2;
    float* el     = (float*)ws;             ws += (size_t)NN * 4;
    float* er     = (float*)ws;             ws += (size_t)NN * 4;
    int*   deg    = (int*)ws;               ws += (size_t)NN * 4;
    int*   off    = (int*)ws;               ws += (size_t)NN * 4;
    int*   ssrc   = (int*)ws;               ws += (size_t)NBUCK * ECAP * 4;
    unsigned* ebuf = (unsigned*)ws;         ws += (size_t)NBUCK * ECAP * 4;
    int*   gcur   = (int*)ws;               ws += (size_t)256 * 4;
    int*   nsplit = (int*)ws;               ws += (size_t)(NGRP + 1) * 4;

    // kA: weight prep + gcur zero
    k_prep<<<PREPB, 256, 0, stream>>>(W, fcW, Wt, fcWt, gcur);
    // kB: CSR binning ∪ gemm1(+el/er), depth-2 pipelined
    fused_bin_gemm1<<<NCHB + G1, 256, 0, stream>>>(src, dst, gcur, ebuf,
                                                   X, Wt, attn_l, attn_r, featb, el, er);
    // kC: per-bucket CSR finalize + local group-boundary resolution
    fused_csr<<<NBUCK, 1024, 0, stream>>>(ebuf, gcur, off, deg, ssrc, nsplit);
    // kE: aggregate
    aggregate<<<NGRP / 16, 256, 0, stream>>>(off, deg, ssrc, el, er, featb, hb, nsplit);
    // kF: output GEMM
    gemm2<<<(NN + 127) / 128, 256, 0, stream>>>(hb, fcWt, fcb, out);
}

// Round 16
// 147.570 us; speedup vs baseline: 1.0898x; 1.0898x over previous
//
#include <hip/hip_runtime.h>
#include <math.h>

#define NN 100000
#define NE 1600000
#define DIN 256
#define DHID 128
#define NCLS 64
#define NEG_SLOPE 0.2f

#define NBUCK 196          // ceil(NN / 512), bucket = dst >> 9
#define ECAP 10240         // fixed per-bucket ebuf capacity (mean 8192, +22 sigma)
#define CHUNK 4096
#define NCHB ((NE + CHUNK - 1) / CHUNK)   // 391
#define PREPB 16

#define NGRP 16384         // edge-balanced 16-lane groups for aggregate
#define G1 ((NN + 127) / 128)             // 782 gemm1 blocks

typedef __bf16 bf16_t;
typedef bf16_t bf16x8 __attribute__((ext_vector_type(8)));
typedef float f32x4 __attribute__((ext_vector_type(4)));
typedef ushort ushort8v __attribute__((ext_vector_type(8)));

__device__ __forceinline__ ushort f2bf(float f) {
    union { float f; unsigned u; } c; c.f = f;
    unsigned u = c.u;
    unsigned r = (u + 0x7FFFu + ((u >> 16) & 1u)) >> 16;
    return (ushort)r;
}
__device__ __forceinline__ float bf2f(ushort b) {
    return __uint_as_float(((unsigned)b) << 16);
}

// ================= kA: weight prep + gcur zero =================
__global__ __launch_bounds__(256) void k_prep(const float* __restrict__ W,
                                              const float* __restrict__ fcW,
                                              ushort* __restrict__ Wt,
                                              ushort* __restrict__ fcWt,
                                              int* __restrict__ gcur) {
    int t = blockIdx.x * 256 + threadIdx.x;
    if (blockIdx.x == 0) gcur[threadIdx.x] = 0;
    for (int i = t; i < DHID * DIN; i += PREPB * 256) {   // Wt[n][k]
        int n = i >> 8, k = i & 255;
        Wt[i] = f2bf(W[k * DHID + n]);
    }
    for (int i = t; i < NCLS * DHID; i += PREPB * 256) {  // fcWt[n][k]
        int n = i >> 7, k = i & 127;
        fcWt[i] = f2bf(fcW[k * NCLS + n]);
    }
}

// ================= kB: k_bin ∪ gemm1 (depth-1, R14-proven) =================
union SmemB {
    struct {                      // k_bin branch (~30 KB)
        int hist[NBUCK];
        int scn[256];
        int loff[NBUCK];
        int cur[NBUCK];
        int gb[NBUCK];
        unsigned ord[CHUNK];
        ushort obk[CHUNK];
    } b;
    struct {                      // gemm1 branch (~65 KB)
        ushort Xs[2][8192];
        ushort Wl[2][8192];
        float Al[DHID];
        float Ar[DHID];
    } g;
};

__global__ __launch_bounds__(256, 2) void fused_bin_gemm1(
        const int* __restrict__ src, const int* __restrict__ dst,
        int* __restrict__ gcur, unsigned* __restrict__ ebuf,
        const float* __restrict__ X, const ushort* __restrict__ Wt,
        const float* __restrict__ attn_l, const float* __restrict__ attn_r,
        ushort* __restrict__ featb, float* __restrict__ el, float* __restrict__ er) {
    __shared__ SmemB sm;
    const int t = threadIdx.x;

    if (blockIdx.x < NCHB) {
        // ---- k_bin branch ----
        const int base = blockIdx.x * CHUNK;
        int cnt = NE - base; if (cnt > CHUNK) cnt = CHUNK;

        for (int i = t; i < NBUCK; i += 256) sm.b.hist[i] = 0;
        __syncthreads();

        unsigned vals[16];
        int bks[16];
#pragma unroll
        for (int i = 0; i < 16; i++) {
            int idx = base + i * 256 + t;
            if (idx < NE) {
                int d = dst[idx], s = src[idx];
                int bb = d >> 9;
                bks[i] = bb;
                vals[i] = ((unsigned)(d & 511) << 17) | (unsigned)s;
                atomicAdd(&sm.b.hist[bb], 1);
            } else bks[i] = -1;
        }
        __syncthreads();

        int hv = (t < NBUCK) ? sm.b.hist[t] : 0;
        sm.b.scn[t] = hv;
        __syncthreads();
        for (int d = 1; d < 256; d <<= 1) {
            int a = (t >= d) ? sm.b.scn[t - d] : 0;
            __syncthreads();
            sm.b.scn[t] += a;
            __syncthreads();
        }
        if (t < NBUCK) { sm.b.loff[t] = sm.b.scn[t] - hv; sm.b.cur[t] = sm.b.scn[t] - hv; }
        __syncthreads();

#pragma unroll
        for (int i = 0; i < 16; i++) {
            if (bks[i] >= 0) {
                int slot = atomicAdd(&sm.b.cur[bks[i]], 1);
                sm.b.ord[slot] = vals[i];
                sm.b.obk[slot] = (ushort)bks[i];
            }
        }
        if (t < NBUCK && hv > 0) sm.b.gb[t] = t * ECAP + atomicAdd(&gcur[t], hv);
        __syncthreads();

        for (int s = t; s < cnt; s += 256) {
            int bb = sm.b.obk[s];
            ebuf[sm.b.gb[bb] + (s - sm.b.loff[bb])] = sm.b.ord[s];
        }
        return;
    }

    // ---- gemm1 branch ----
    const int row0 = (blockIdx.x - NCHB) * 128;
    if (t < 128) { sm.g.Al[t] = attn_l[t]; sm.g.Ar[t] = attn_r[t]; }

    int srow[4], ske[4];
#pragma unroll
    for (int i = 0; i < 4; i++) {
        int o = i * 4096 + t * 16;
        int row = o >> 7;
        int bl = (o & 127) ^ ((row & 7) << 4);
        srow[i] = row;
        ske[i] = bl >> 1;
    }

    float4 xr[4][2];
    uint4  wr[4];

#pragma unroll
    for (int i = 0; i < 4; i++) {
        int grow = row0 + srow[i];
        if (grow < NN) {
            const float4* p = (const float4*)(X + (size_t)grow * DIN + ske[i]);
            xr[i][0] = p[0]; xr[i][1] = p[1];
        } else {
            xr[i][0] = make_float4(0.f, 0.f, 0.f, 0.f);
            xr[i][1] = make_float4(0.f, 0.f, 0.f, 0.f);
        }
        wr[i] = *(const uint4*)(Wt + (size_t)srow[i] * DIN + ske[i]);
    }
#pragma unroll
    for (int i = 0; i < 4; i++) {
        int o = i * 4096 + t * 16;
        ushort8v b;
        b[0] = f2bf(xr[i][0].x); b[1] = f2bf(xr[i][0].y);
        b[2] = f2bf(xr[i][0].z); b[3] = f2bf(xr[i][0].w);
        b[4] = f2bf(xr[i][1].x); b[5] = f2bf(xr[i][1].y);
        b[6] = f2bf(xr[i][1].z); b[7] = f2bf(xr[i][1].w);
        *(ushort8v*)((char*)&sm.g.Xs[0][0] + o) = b;
        *(uint4*)((char*)&sm.g.Wl[0][0] + o) = wr[i];
    }
    __syncthreads();

    const int w = t >> 6, lane = t & 63;
    const int rbase = w * 32;
    const int lcol = lane & 15;
    const int kgrp = (lane >> 4) * 16;

    f32x4 acc[2][8];
#pragma unroll
    for (int r = 0; r < 2; r++)
#pragma unroll
        for (int c = 0; c < 8; c++) acc[r][c] = (f32x4){0.f, 0.f, 0.f, 0.f};

    for (int c = 0; c < 4; c++) {
        const int buf = c & 1;
        if (c < 3) {
            int k0g = (c + 1) * 64;
#pragma unroll
            for (int i = 0; i < 4; i++) {
                int grow = row0 + srow[i];
                if (grow < NN) {
                    const float4* p = (const float4*)(X + (size_t)grow * DIN + k0g + ske[i]);
                    xr[i][0] = p[0]; xr[i][1] = p[1];
                } else {
                    xr[i][0] = make_float4(0.f, 0.f, 0.f, 0.f);
                    xr[i][1] = make_float4(0.f, 0.f, 0.f, 0.f);
                }
                wr[i] = *(const uint4*)(Wt + (size_t)srow[i] * DIN + k0g + ske[i]);
            }
        }
        const char* xb = (const char*)&sm.g.Xs[buf][0];
        const char* wb = (const char*)&sm.g.Wl[buf][0];
#pragma unroll
        for (int k0 = 0; k0 < 2; k0++) {
            int kb = k0 * 64 + kgrp;
            bf16x8 a[2], b[8];
#pragma unroll
            for (int r = 0; r < 2; r++) {
                int row = rbase + r * 16 + lcol;
                a[r] = *(const bf16x8*)(xb + row * 128 + (kb ^ ((row & 7) << 4)));
            }
#pragma unroll
            for (int cc = 0; cc < 8; cc++) {
                int n = cc * 16 + lcol;
                b[cc] = *(const bf16x8*)(wb + n * 128 + (kb ^ ((n & 7) << 4)));
            }
#pragma unroll
            for (int r = 0; r < 2; r++)
#pragma unroll
                for (int cc = 0; cc < 8; cc++)
                    acc[r][cc] = __builtin_amdgcn_mfma_f32_16x16x32_bf16(a[r], b[cc], acc[r][cc], 0, 0, 0);
        }
        if (c < 3) {
#pragma unroll
            for (int i = 0; i < 4; i++) {
                int o = i * 4096 + t * 16;
                ushort8v b;
                b[0] = f2bf(xr[i][0].x); b[1] = f2bf(xr[i][0].y);
                b[2] = f2bf(xr[i][0].z); b[3] = f2bf(xr[i][0].w);
                b[4] = f2bf(xr[i][1].x); b[5] = f2bf(xr[i][1].y);
                b[6] = f2bf(xr[i][1].z); b[7] = f2bf(xr[i][1].w);
                *(ushort8v*)((char*)&sm.g.Xs[buf ^ 1][0] + o) = b;
                *(uint4*)((char*)&sm.g.Wl[buf ^ 1][0] + o) = wr[i];
            }
        }
        __syncthreads();
    }

    ushort* Os = (ushort*)sm.g.Xs;
#pragma unroll
    for (int r = 0; r < 2; r++)
#pragma unroll
        for (int cc = 0; cc < 8; cc++)
#pragma unroll
            for (int i = 0; i < 4; i++) {
                int rloc = rbase + r * 16 + (lane >> 4) * 4 + i;
                int col = cc * 16 + lcol;
                Os[rloc * 128 + col] = f2bf(acc[r][cc][i]);
            }
    __syncthreads();

    // fused el/er: 2 threads per row, row-rotated LDS reads
    {
        int row = t >> 1, half = t & 1;
        int grow = row0 + row;
        const ushort* orow = Os + row * 128 + half * 64;
        const float* alp = sm.g.Al + half * 64;
        const float* arp = sm.g.Ar + half * 64;
        float pl = 0.f, pr = 0.f;
        int rot = row & 7;
#pragma unroll
        for (int qq = 0; qq < 8; qq++) {
            int q = (qq + rot) & 7;
            ushort8v f8 = *(const ushort8v*)(orow + q * 8);
#pragma unroll
            for (int e = 0; e < 8; e++) {
                float fe = bf2f(f8[e]);
                pl += fe * alp[q * 8 + e];
                pr += fe * arp[q * 8 + e];
            }
        }
        pl += __shfl_down(pl, 1);
        pr += __shfl_down(pr, 1);
        if (!half && grow < NN) { el[grow] = pl; er[grow] = pr; }
    }

#pragma unroll
    for (int i = 0; i < 8; i++) {
        int u = i * 256 + t;
        int row = u >> 4;
        int grow = row0 + row;
        if (grow < NN)
            *(uint4*)(featb + (size_t)grow * 128 + (u & 15) * 8) =
                *(uint4*)((char*)Os + u * 16);
    }
}

// ================= kC: k_csr + local group-boundary resolution (1024 thr) =================
__global__ __launch_bounds__(1024) void fused_csr(const unsigned* __restrict__ ebuf,
                                                  const int* __restrict__ gcur,
                                                  int* __restrict__ off_g,
                                                  int* __restrict__ deg_g,
                                                  int* __restrict__ ssrc,
                                                  int* __restrict__ nsplit) {
    __shared__ int sdeg[512];
    __shared__ int pr[256];
    __shared__ int lofs[512];
    __shared__ int scnt[512];
    __shared__ int sb[2];   // [0]=bpre_b, [1]=total
    const int b = blockIdx.x, t = threadIdx.x;
    const int node0 = b << 9;
    const int ebase = b * ECAP;
    const int ecnt = gcur[b];

    // bucket prefix (196 entries, t<256 active in scan)
    if (t < 256) pr[t] = (t < NBUCK) ? gcur[t] : 0;
    __syncthreads();
    for (int d = 1; d < 256; d <<= 1) {
        int a = 0;
        if (t < 256 && t >= d) a = pr[t - d];
        __syncthreads();
        if (t < 256) pr[t] += a;
        __syncthreads();
    }
    if (t == 0) { sb[0] = pr[b] - ecnt; sb[1] = pr[NBUCK - 1]; }
    if (t < 512) sdeg[t] = 0;
    __syncthreads();

    for (int s = t; s < ecnt; s += 1024)
        atomicAdd(&sdeg[ebuf[ebase + s] >> 17], 1);
    __syncthreads();

    int d0 = 0, d1 = 0;
    if (t < 256) { d0 = sdeg[2 * t]; d1 = sdeg[2 * t + 1]; pr[t] = d0 + d1; }
    __syncthreads();
    for (int d = 1; d < 256; d <<= 1) {
        int a = 0;
        if (t < 256 && t >= d) a = pr[t - d];
        __syncthreads();
        if (t < 256) pr[t] += a;
        __syncthreads();
    }
    if (t < 256) {
        int ex = pr[t] - d0 - d1;
        lofs[2 * t] = ex;
        lofs[2 * t + 1] = ex + d0;
        scnt[2 * t] = 0; scnt[2 * t + 1] = 0;
        int n0 = node0 + 2 * t, n1 = n0 + 1;
        if (n0 < NN) { off_g[n0] = ebase + ex;      deg_g[n0] = d0; }
        if (n1 < NN) { off_g[n1] = ebase + ex + d0; deg_g[n1] = d1; }
    }
    __syncthreads();

    // scatter
    for (int s = t; s < ecnt; s += 1024) {
        unsigned v = ebuf[ebase + s];
        int dl = v >> 17;
        int c = atomicAdd(&scnt[dl], 1);
        ssrc[ebase + lofs[dl] + c] = (int)(v & 0x1FFFFu);
    }

    // group boundaries whose targets land in this bucket's real-edge range
    {
        long bpre_b = sb[0], total = sb[1];
        if (total > 0 && ecnt > 0) {
            long glo = (bpre_b * NGRP + total - 1) / total;
            long ghi = ((bpre_b + ecnt) * NGRP + total - 1) / total;
            if (ghi > NGRP) ghi = NGRP;
            for (long g = glo + t; g < ghi; g += 1024) {
                long target = g * total / NGRP;
                int lt = (int)(target - bpre_b);
                int lo = 0, hi = 512;
                while (lo < hi) {
                    int m = (lo + hi) >> 1;
                    if (lofs[m] < lt) lo = m + 1; else hi = m;
                }
                int node = node0 + lo;
                if (node > NN) node = NN;
                nsplit[g] = node;
            }
        }
        if (b == 0 && t == 0) nsplit[NGRP] = NN;
    }
}

// ================= kE: aggregate (full-row, 4-deep, nsplit array) =================
__global__ __launch_bounds__(256) void aggregate(const int* __restrict__ off,
                                                 const int* __restrict__ deg,
                                                 const int* __restrict__ ssrc,
                                                 const float* __restrict__ el,
                                                 const float* __restrict__ er,
                                                 const ushort* __restrict__ featb,
                                                 ushort* __restrict__ hb,
                                                 const int* __restrict__ nsplit) {
    const int gid = blockIdx.x * 16 + (threadIdx.x >> 4);
    const int lc = threadIdx.x & 15;
    int n = nsplit[gid];
    const int nend = nsplit[gid + 1];
    const ushort* fb = featb + lc * 8;

    for (; n < nend; ++n) {
        const int e0 = off[n];
        const int dg = deg[n];
        const float erd = er[n];
        float acc[8];
#pragma unroll
        for (int q = 0; q < 8; q++) acc[q] = 0.f;
        float wsum = 0.f;

        int j = 0;
        for (; j + 4 <= dg; j += 4) {
            int s0 = ssrc[e0 + j + 0];
            int s1 = ssrc[e0 + j + 1];
            int s2 = ssrc[e0 + j + 2];
            int s3 = ssrc[e0 + j + 3];
            ushort8v f0 = *(const ushort8v*)(fb + (size_t)s0 * DHID);
            ushort8v f1 = *(const ushort8v*)(fb + (size_t)s1 * DHID);
            ushort8v f2 = *(const ushort8v*)(fb + (size_t)s2 * DHID);
            ushort8v f3 = *(const ushort8v*)(fb + (size_t)s3 * DHID);
            float x0 = el[s0] + erd, x1 = el[s1] + erd;
            float x2 = el[s2] + erd, x3 = el[s3] + erd;
            x0 = x0 > 0.f ? x0 : NEG_SLOPE * x0;
            x1 = x1 > 0.f ? x1 : NEG_SLOPE * x1;
            x2 = x2 > 0.f ? x2 : NEG_SLOPE * x2;
            x3 = x3 > 0.f ? x3 : NEG_SLOPE * x3;
            float w0 = __expf(x0), w1 = __expf(x1);
            float w2 = __expf(x2), w3 = __expf(x3);
            wsum += (w0 + w1) + (w2 + w3);
#pragma unroll
            for (int q = 0; q < 8; q++)
                acc[q] += (w0 * bf2f(f0[q]) + w1 * bf2f(f1[q])) +
                          (w2 * bf2f(f2[q]) + w3 * bf2f(f3[q]));
        }
        for (; j < dg; ++j) {
            int s0 = ssrc[e0 + j];
            ushort8v f0 = *(const ushort8v*)(fb + (size_t)s0 * DHID);
            float x0 = el[s0] + erd;
            x0 = x0 > 0.f ? x0 : NEG_SLOPE * x0;
            float w0 = __expf(x0);
            wsum += w0;
#pragma unroll
            for (int q = 0; q < 8; q++) acc[q] += w0 * bf2f(f0[q]);
        }

        float inv = (dg > 0) ? 1.0f / wsum : 0.f;
        ushort8v o8;
#pragma unroll
        for (int q = 0; q < 8; q++) o8[q] = f2bf(acc[q] * inv);
        *(ushort8v*)(hb + (size_t)n * DHID + lc * 8) = o8;
    }
}

// ================= kF: GEMM2 =================
__global__ __launch_bounds__(256, 3) void gemm2(const ushort* __restrict__ hb,
                                                const ushort* __restrict__ fcWt,
                                                const float* __restrict__ fcb,
                                                float* __restrict__ out) {
    __shared__ ushort Hs[128 * 128];   // 32 KB
    __shared__ ushort Fs[64 * 128];    // 16 KB
    const int t = threadIdx.x;
    const int row0 = blockIdx.x * 128;

    {
#pragma unroll
        for (int i = 0; i < 8; i++) {
            int u = i * 256 + t;
            int row = u >> 4;
            int grow = row0 + row;
            uint4 v = make_uint4(0, 0, 0, 0);
            if (grow < NN) v = *(const uint4*)(hb + (size_t)grow * 128 + (u & 15) * 8);
            int byte_off = row * 256 + (((u & 15) * 16) ^ ((row & 7) << 4));
            *(uint4*)((char*)Hs + byte_off) = v;
        }
#pragma unroll
        for (int i = 0; i < 4; i++) {
            int u = i * 256 + t;
            int n = u >> 4;
            int byte_off = n * 256 + (((u & 15) * 16) ^ ((n & 7) << 4));
            *(uint4*)((char*)Fs + byte_off) = ((const uint4*)fcWt)[u];
        }
    }

    const int w = t >> 6, lane = t & 63;
    const int rbase = w * 32;
    const int lcol = lane & 15;
    const int kgrp = (lane >> 4) * 16;

    f32x4 acc[2][4];
#pragma unroll
    for (int c = 0; c < 4; c++) {
        float bias = fcb[c * 16 + lcol];
#pragma unroll
        for (int r = 0; r < 2; r++)
#pragma unroll
            for (int i = 0; i < 4; i++) acc[r][c][i] = bias;
    }
    __syncthreads();

#pragma unroll
    for (int k0 = 0; k0 < 4; k0++) {
        int kbyte = k0 * 64 + kgrp;
        bf16x8 a[2], b[4];
#pragma unroll
        for (int r = 0; r < 2; r++) {
            int row = rbase + r * 16 + lcol;
            a[r] = *(bf16x8*)((char*)Hs + row * 256 + (kbyte ^ ((row & 7) << 4)));
        }
#pragma unroll
        for (int c = 0; c < 4; c++) {
            int n = c * 16 + lcol;
            b[c] = *(bf16x8*)((char*)Fs + n * 256 + (kbyte ^ ((n & 7) << 4)));
        }
#pragma unroll
        for (int r = 0; r < 2; r++)
#pragma unroll
            for (int c = 0; c < 4; c++)
                acc[r][c] = __builtin_amdgcn_mfma_f32_16x16x32_bf16(a[r], b[c], acc[r][c], 0, 0, 0);
    }

#pragma unroll
    for (int r = 0; r < 2; r++)
#pragma unroll
        for (int i = 0; i < 4; i++) {
            int row = rbase + r * 16 + (lane >> 4) * 4 + i;
            int grow = row0 + row;
            if (grow < NN) {
                float* op = out + (size_t)grow * 64 + lcol;
#pragma unroll
                for (int c = 0; c < 4; c++) op[c * 16] = acc[r][c][i];
            }
        }
}

// ---------------- launch ----------------
extern "C" void kernel_launch(void* const* d_in, const int* in_sizes, int n_in,
                              void* d_out, int out_size, void* d_ws, size_t ws_size,
                              hipStream_t stream) {
    const float* X      = (const float*)d_in[0];
    const float* W      = (const float*)d_in[1];
    const float* attn_l = (const float*)d_in[2];
    const float* attn_r = (const float*)d_in[3];
    const float* fcW    = (const float*)d_in[4];
    const float* fcb    = (const float*)d_in[5];
    const int*   src    = (const int*)d_in[6];
    const int*   dst    = (const int*)d_in[7];
    float* out = (float*)d_out;

    char* ws = (char*)d_ws;
    ushort* featb = (ushort*)ws;            ws += (size_t)NN * DHID * 2;
    ushort* hb    = (ushort*)ws;            ws += (size_t)NN * DHID * 2;
    ushort* Wt    = (ushort*)ws;            ws += (size_t)DHID * DIN * 2;
    ushort* fcWt  = (ushort*)ws;            ws += (size_t)NCLS * DHID * 2;
    float* el     = (float*)ws;             ws += (size_t)NN * 4;
    float* er     = (float*)ws;             ws += (size_t)NN * 4;
    int*   deg    = (int*)ws;               ws += (size_t)NN * 4;
    int*   off    = (int*)ws;               ws += (size_t)NN * 4;
    int*   ssrc   = (int*)ws;               ws += (size_t)NBUCK * ECAP * 4;
    unsigned* ebuf = (unsigned*)ws;         ws += (size_t)NBUCK * ECAP * 4;
    int*   gcur   = (int*)ws;               ws += (size_t)256 * 4;
    int*   nsplit = (int*)ws;               ws += (size_t)(NGRP + 1) * 4;

    // kA: weight prep + gcur zero
    k_prep<<<PREPB, 256, 0, stream>>>(W, fcW, Wt, fcWt, gcur);
    // kB: CSR binning ∪ gemm1(+el/er) — depth-1, co-resident
    fused_bin_gemm1<<<NCHB + G1, 256, 0, stream>>>(src, dst, gcur, ebuf,
                                                   X, Wt, attn_l, attn_r, featb, el, er);
    // kC: per-bucket CSR finalize + local group-boundary resolution
    fused_csr<<<NBUCK, 1024, 0, stream>>>(ebuf, gcur, off, deg, ssrc, nsplit);
    // kE: aggregate
    aggregate<<<NGRP / 16, 256, 0, stream>>>(off, deg, ssrc, el, er, featb, hb, nsplit);
    // kF: output GEMM
    gemm2<<<(NN + 127) / 128, 256, 0, stream>>>(hb, fcWt, fcb, out);
}